// Round 2
// baseline (26.925 us; speedup 1.0000x reference)
//
#include <hip/hip_runtime.h>
#include <stdint.h>

#define K_DIM 4096
#define KW 1024          // packed words per m-row (1 word = low byte = 4 ternary k-values... per ref: 1 int32 element holds 4 k in low byte)
#define M_DIM 11008
#define B_DIM 16
#define GROUP_ROWS 2752  // M / 4 groups
#define CHUNK_W 256      // words per chunk (K split in 4 chunks of 1024 k)

// spread the low byte of p (4x 2-bit fields) into 4 bytes: {p&3,(p>>2)&3,(p>>4)&3,(p>>6)&3}
__device__ __forceinline__ int spread2(int p) {
    int t = p | (p << 12);
    return (t & 0x00030003) | (((t >> 2) & 0x00030003) << 8);
}
__device__ __forceinline__ int dot4(int a, int b, int c) {
    return __builtin_amdgcn_sdot4(a, b, c, false);
}

// ---------------- kernel 1: per-row activation quantization ----------------
// 16 blocks (one per batch row) x 256 threads. Writes q packed int8 [b][KW] words,
// per-row sum(q) and 1/s.
__global__ __launch_bounds__(256) void quant_k(const float* __restrict__ in,
                                               int* __restrict__ qg,
                                               int* __restrict__ sumq,
                                               float* __restrict__ invs) {
    const int b = blockIdx.x;
    const int t = threadIdx.x;
    const int lane = t & 63, wid = t >> 6;

    const float4* row = (const float4*)(in + (size_t)b * K_DIM);
    float4 v[4];
#pragma unroll
    for (int i = 0; i < 4; ++i) v[i] = row[t * 4 + i];

    float mx = 0.f;
#pragma unroll
    for (int i = 0; i < 4; ++i) {
        mx = fmaxf(mx, fabsf(v[i].x)); mx = fmaxf(mx, fabsf(v[i].y));
        mx = fmaxf(mx, fabsf(v[i].z)); mx = fmaxf(mx, fabsf(v[i].w));
    }
#pragma unroll
    for (int s = 1; s < 64; s <<= 1) mx = fmaxf(mx, __shfl_xor(mx, s, 64));

    __shared__ float wmax[4];
    __shared__ int wsum[4];
    if (lane == 0) wmax[wid] = mx;
    __syncthreads();
    const float bm = fmaxf(fmaxf(wmax[0], wmax[1]), fmaxf(wmax[2], wmax[3]));
    const float sc = 127.f / fmaxf(bm, 1e-5f);

    int ss = 0;
    int pk[4];
#pragma unroll
    for (int i = 0; i < 4; ++i) {
        float xs[4] = {v[i].x, v[i].y, v[i].z, v[i].w};
        int w = 0;
#pragma unroll
        for (int j = 0; j < 4; ++j) {
            int q = (int)rintf(xs[j] * sc);           // round-half-even, matches jnp.round
            q = q > 127 ? 127 : (q < -128 ? -128 : q);
            ss += q;
            w |= (q & 255) << (8 * j);
        }
        pk[i] = w;
    }
    // linear layout: qg[b][KW]; thread t owns words t*4..t*4+3
    *(int4*)(qg + b * KW + t * 4) = *(int4*)pk;

#pragma unroll
    for (int s = 1; s < 64; s <<= 1) ss += __shfl_xor(ss, s, 64);
    if (lane == 0) wsum[wid] = ss;
    __syncthreads();
    if (t == 0) {
        sumq[b] = wsum[0] + wsum[1] + wsum[2] + wsum[3];
        invs[b] = fmaxf(bm, 1e-5f) / 127.f;
    }
}

// ---------------- kernel 2: ternary GEMM via sdot4, barrier-free ----------------
// grid = M/4 blocks of ONE wave (64 threads); wave owns 4 m-rows, lanes split K.
// q read directly from global (64 KB, L2/L1-resident broadcast). No LDS, no barriers.
__global__ __launch_bounds__(64) void gemm_k(const int* __restrict__ wp,
                                             const int* __restrict__ qg,
                                             const int* __restrict__ sumq,
                                             const float* __restrict__ invs,
                                             const float* __restrict__ wscale,
                                             float* __restrict__ out) {
    const int lane = threadIdx.x;
    const int m0 = blockIdx.x * 4;

    const int* wb = wp + (size_t)m0 * KW + lane * 4;  // lane's 16-k slice, m stride KW

    int acc[64];
#pragma unroll
    for (int i = 0; i < 64; ++i) acc[i] = 0;

    int4 w[4], wn[4];
#pragma unroll
    for (int m = 0; m < 4; ++m) w[m] = *(const int4*)(wb + m * KW);

#pragma unroll
    for (int c = 0; c < 4; ++c) {
        // prefetch next chunk's weights while dotting this one
        if (c < 3) {
#pragma unroll
            for (int m = 0; m < 4; ++m)
                wn[m] = *(const int4*)(wb + (c + 1) * CHUNK_W + m * KW);
        }
        int sp[4][4];
#pragma unroll
        for (int m = 0; m < 4; ++m) {
            sp[m][0] = spread2(w[m].x); sp[m][1] = spread2(w[m].y);
            sp[m][2] = spread2(w[m].z); sp[m][3] = spread2(w[m].w);
        }
        const int* qb = qg + c * CHUNK_W + lane * 4;
#pragma unroll
        for (int b = 0; b < B_DIM; ++b) {
            int4 q = *(const int4*)(qb + b * KW);
            const int bi = b * 4;
#pragma unroll
            for (int m = 0; m < 4; ++m) {
                int a = acc[bi + m];
                a = dot4(q.x, sp[m][0], a);
                a = dot4(q.y, sp[m][1], a);
                a = dot4(q.z, sp[m][2], a);
                a = dot4(q.w, sp[m][3], a);
                acc[bi + m] = a;
            }
        }
#pragma unroll
        for (int m = 0; m < 4; ++m) w[m] = wn[m];
    }

    // butterfly halving reduction: 64 accs over 64 lanes -> 1 acc/lane (63 shuffles)
#define RSTAGE(S, N)                                           \
    {                                                          \
        const bool up = (lane & S) != 0;                       \
        _Pragma("unroll") for (int i = 0; i < N; ++i) {        \
            int snd = up ? acc[i] : acc[i + N];                \
            int kp  = up ? acc[i + N] : acc[i];                \
            acc[i] = kp + __shfl_xor(snd, S, 64);              \
        }                                                      \
    }
    RSTAGE(1, 32) RSTAGE(2, 16) RSTAGE(4, 8) RSTAGE(8, 4) RSTAGE(16, 2) RSTAGE(32, 1)
#undef RSTAGE

    // lane l holds acc index a = bitrev6(l); a = b*4 + msub
    const int a = ((lane & 1) << 5) | ((lane & 2) << 3) | ((lane & 4) << 1) |
                  ((lane & 8) >> 1) | ((lane & 16) >> 3) | ((lane & 32) >> 5);
    const int b = a >> 2, ms = a & 3;
    const int mr = m0 + ms;
    const float val = (float)(acc[0] - sumq[b]) * invs[b] * wscale[mr / GROUP_ROWS];
    out[(size_t)b * M_DIM + mr] = val;
}

extern "C" void kernel_launch(void* const* d_in, const int* in_sizes, int n_in,
                              void* d_out, int out_size, void* d_ws, size_t ws_size,
                              hipStream_t stream) {
    const float* inp    = (const float*)d_in[0];
    const int*   wp     = (const int*)d_in[1];
    const float* wscale = (const float*)d_in[2];
    float* out = (float*)d_out;

    int*   qg   = (int*)d_ws;                 // 16384 words = 64 KB
    int*   sumq = qg + B_DIM * KW;            // 16 ints
    float* invs = (float*)(sumq + B_DIM);     // 16 floats

    quant_k<<<dim3(B_DIM), dim3(256), 0, stream>>>(inp, qg, sumq, invs);
    gemm_k<<<dim3(M_DIM / 4), dim3(64), 0, stream>>>(wp, qg, sumq, invs, wscale, out);
}

// Round 3
// 22.520 us; speedup vs baseline: 1.1956x; 1.1956x over previous
//
#include <hip/hip_runtime.h>
#include <stdint.h>

#define K_DIM 4096
#define KW 1024          // packed words per m-row (4 ternary values in low byte of each int32)
#define M_DIM 11008
#define B_DIM 16
#define GROUP_ROWS 2752  // M / 4 groups

typedef int v4i __attribute__((ext_vector_type(4)));

// spread low byte p (4x 2-bit fields) into 4 bytes: {p&3,(p>>2)&3,(p>>4)&3,(p>>6)&3}
__device__ __forceinline__ int spread2(int p) {
    int t = p | (p << 12);
    return (t & 0x00030003) | (((t >> 2) & 0x00030003) << 8);
}

// ---------------- kernel 1: per-row activation quantization ----------------
// 16 blocks x 1024 threads; thread t quantizes 4 floats -> one packed int32 word.
__global__ __launch_bounds__(1024) void quant_k(const float* __restrict__ in,
                                                int* __restrict__ qg,
                                                int* __restrict__ sumq,
                                                float* __restrict__ invs) {
    const int b = blockIdx.x, t = threadIdx.x;
    const int lane = t & 63, wid = t >> 6;  // 16 waves

    float4 v = ((const float4*)(in + (size_t)b * K_DIM))[t];
    float mx = fmaxf(fmaxf(fabsf(v.x), fabsf(v.y)), fmaxf(fabsf(v.z), fabsf(v.w)));
#pragma unroll
    for (int s = 1; s < 64; s <<= 1) mx = fmaxf(mx, __shfl_xor(mx, s, 64));

    __shared__ float wmax[16];
    __shared__ int wsum[16];
    if (lane == 0) wmax[wid] = mx;
    __syncthreads();
    float bm = wmax[0];
#pragma unroll
    for (int i = 1; i < 16; ++i) bm = fmaxf(bm, wmax[i]);
    const float sc = 127.f / fmaxf(bm, 1e-5f);

    float xs[4] = {v.x, v.y, v.z, v.w};
    int w = 0, ss = 0;
#pragma unroll
    for (int j = 0; j < 4; ++j) {
        int q = (int)rintf(xs[j] * sc);   // round-half-even, matches jnp.round
        q = q > 127 ? 127 : (q < -128 ? -128 : q);
        ss += q;
        w |= (q & 255) << (8 * j);
    }
    qg[b * KW + t] = w;

#pragma unroll
    for (int s = 1; s < 64; s <<= 1) ss += __shfl_xor(ss, s, 64);
    if (lane == 0) wsum[wid] = ss;
    __syncthreads();
    if (t == 0) {
        int tot = 0;
#pragma unroll
        for (int i = 0; i < 16; ++i) tot += wsum[i];
        sumq[b] = tot;
        invs[b] = fmaxf(bm, 1e-5f) / 127.f;
    }
}

// ---------------- kernel 2: ternary GEMM via mfma_i32_16x16x64_i8 ----------------
// 688 blocks x 256 threads (4 waves). Block owns a 16b x 16m output tile;
// wave `wid` accumulates its K-quarter (16 MFMA steps of K=64); LDS reduce at end.
// A fragment (q): lane holds b = lane&15, k = kbase + (lane>>4)*16 + 0..15 (one int4).
// B fragment (w): lane holds m = m0 + (lane&15), same k-slice, from 4 packed words.
__global__ __launch_bounds__(256) void gemm_k(const int* __restrict__ wp,
                                              const int* __restrict__ qg,
                                              const int* __restrict__ sumq,
                                              const float* __restrict__ invs,
                                              const float* __restrict__ wscale,
                                              float* __restrict__ out) {
    __shared__ int red[4][64][4];  // 4 KB
    const int t = threadIdx.x, lane = t & 63, wid = t >> 6;
    const int m0 = blockIdx.x * 16;
    const int lrow = lane & 15;    // b for A, m-offset for B
    const int lgrp = lane >> 4;    // k-group within the 64-k step
    const int wbase = wid * 256 + lgrp * 4;  // word offset within a row (this wave's K-quarter)

    const int* wptr = wp + (size_t)(m0 + lrow) * KW + wbase;
    const int* qptr = qg + lrow * KW + wbase;

    // q[0] first, then ALL 16 weight int4s: 17 loads in flight, HBM latency fully covered.
    v4i qv0 = *(const v4i*)qptr;
    v4i wv[16];
#pragma unroll
    for (int s = 0; s < 16; ++s) wv[s] = *(const v4i*)(wptr + s * 16);

    v4i acc = {0, 0, 0, 0};
    v4i qA = qv0, qB;
#pragma unroll
    for (int s = 0; s < 16; ++s) {
        // double-buffered q prefetch (L2-resident)
        if (s < 15) {
            if ((s & 1) == 0) qB = *(const v4i*)(qptr + (s + 1) * 16);
            else              qA = *(const v4i*)(qptr + (s + 1) * 16);
        }
        v4i bb;
        bb[0] = spread2(wv[s][0]); bb[1] = spread2(wv[s][1]);
        bb[2] = spread2(wv[s][2]); bb[3] = spread2(wv[s][3]);
        v4i aa = ((s & 1) == 0) ? qA : qB;
        acc = __builtin_amdgcn_mfma_i32_16x16x64_i8(aa, bb, acc, 0, 0, 0);
    }

    *((v4i*)&red[wid][lane][0]) = acc;
    __syncthreads();

    // thread t -> output (b = t>>4, m = t&15); D layout: col=lane&15, row=(lane>>4)*4+reg
    const int b = t >> 4, m = t & 15;
    const int src_lane = ((b >> 2) << 4) | m;
    const int reg = b & 3;
    int sum = red[0][src_lane][reg] + red[1][src_lane][reg] +
              red[2][src_lane][reg] + red[3][src_lane][reg];
    const float gscale = wscale[m0 / GROUP_ROWS];  // block fully inside one group (2752 % 16 == 0)
    const float val = (float)(sum - sumq[b]) * invs[b] * gscale;
    out[(size_t)b * M_DIM + m0 + m] = val;
}

extern "C" void kernel_launch(void* const* d_in, const int* in_sizes, int n_in,
                              void* d_out, int out_size, void* d_ws, size_t ws_size,
                              hipStream_t stream) {
    const float* inp    = (const float*)d_in[0];
    const int*   wp     = (const int*)d_in[1];
    const float* wscale = (const float*)d_in[2];
    float* out = (float*)d_out;

    int*   qg   = (int*)d_ws;               // 16384 words = 64 KB
    int*   sumq = qg + B_DIM * KW;          // 16 ints
    float* invs = (float*)(sumq + B_DIM);   // 16 floats

    quant_k<<<dim3(B_DIM), dim3(1024), 0, stream>>>(inp, qg, sumq, invs);
    gemm_k<<<dim3(M_DIM / 16), dim3(256), 0, stream>>>(wp, qg, sumq, invs, wscale, out);
}

// Round 4
// 21.236 us; speedup vs baseline: 1.2679x; 1.0604x over previous
//
#include <hip/hip_runtime.h>
#include <stdint.h>

#define K_DIM 4096
#define KW 1024          // packed words per m-row
#define M_DIM 11008
#define B_DIM 16
#define GROUP_ROWS 2752  // M / 4 groups
#define QTR_W 256        // words per row per K-quarter

typedef int v4i __attribute__((ext_vector_type(4)));

// spread low byte p (4x 2-bit fields) into 4 bytes: {p&3,(p>>2)&3,(p>>4)&3,(p>>6)&3}
__device__ __forceinline__ int spread2(int p) {
    int t = p | (p << 12);
    return (t & 0x00030003) | (((t >> 2) & 0x00030003) << 8);
}

// ---------------- kernel 1: per-row activation quantization ----------------
__global__ __launch_bounds__(1024) void quant_k(const float* __restrict__ in,
                                                int* __restrict__ qg,
                                                int* __restrict__ sumq,
                                                float* __restrict__ invs) {
    const int b = blockIdx.x, t = threadIdx.x;
    const int lane = t & 63, wid = t >> 6;  // 16 waves

    float4 v = ((const float4*)(in + (size_t)b * K_DIM))[t];
    float mx = fmaxf(fmaxf(fabsf(v.x), fabsf(v.y)), fmaxf(fabsf(v.z), fabsf(v.w)));
#pragma unroll
    for (int s = 1; s < 64; s <<= 1) mx = fmaxf(mx, __shfl_xor(mx, s, 64));

    __shared__ float wmax[16];
    __shared__ int wsum[16];
    if (lane == 0) wmax[wid] = mx;
    __syncthreads();
    float bm = wmax[0];
#pragma unroll
    for (int i = 1; i < 16; ++i) bm = fmaxf(bm, wmax[i]);
    const float sc = 127.f / fmaxf(bm, 1e-5f);

    float xs[4] = {v.x, v.y, v.z, v.w};
    int w = 0, ss = 0;
#pragma unroll
    for (int j = 0; j < 4; ++j) {
        int q = (int)rintf(xs[j] * sc);   // round-half-even, matches jnp.round
        q = q > 127 ? 127 : (q < -128 ? -128 : q);
        ss += q;
        w |= (q & 255) << (8 * j);
    }
    qg[b * KW + t] = w;

#pragma unroll
    for (int s = 1; s < 64; s <<= 1) ss += __shfl_xor(ss, s, 64);
    if (lane == 0) wsum[wid] = ss;
    __syncthreads();
    if (t == 0) {
        int tot = 0;
#pragma unroll
        for (int i = 0; i < 16; ++i) tot += wsum[i];
        sumq[b] = tot;
        invs[b] = fmaxf(bm, 1e-5f) / 127.f;
    }
}

// ---------------- kernel 2: ternary GEMM via mfma_i32_16x16x64_i8 ----------------
// 688 blocks x 256 threads (4 waves); 16 m-rows per block; K in 4 quarters of
// 256 words/row, double-buffered through LDS (2 x 16 KB).
// Staging: wave wid, round r loads row r*4+wid, 64 lanes x 16 B = 1 KB CONTIGUOUS.
// LDS slot = row*64 + (chunk ^ (row&7))  -> ds_read_b128 fragments at <=2-way conflict.
// Raw s_barrier (not __syncthreads) so prefetched loads stay in flight (counted vmcnt).
__global__ __launch_bounds__(256) void gemm_k(const int* __restrict__ wp,
                                              const int* __restrict__ qg,
                                              const int* __restrict__ sumq,
                                              const float* __restrict__ invs,
                                              const float* __restrict__ wscale,
                                              float* __restrict__ out) {
    __shared__ v4i buf[2][1024];  // 2 x 16 KB
    const int t = threadIdx.x, lane = t & 63, wid = t >> 6;
    const int m0 = blockIdx.x * 16;
    const int lrow = lane & 15;   // b for A-frag, m-offset for B-frag
    const int lgrp = lane >> 4;   // k-group within the 64-k MFMA step

    // q: lane reads b=lrow, words q*256 + wid*64 + s*16 + lgrp*4 (same k-slice as B-frag)
    const int* qbase = qg + lrow * KW + wid * 64 + lgrp * 4;

    v4i acc = {0, 0, 0, 0};
    v4i wst[4];
    v4i qb[2][4];

    // ---- prologue: quarter 0 ----
#pragma unroll
    for (int r = 0; r < 4; ++r) {
        const int row = r * 4 + wid;
        wst[r] = *(const v4i*)(wp + (size_t)(m0 + row) * KW + lane * 4);
    }
#pragma unroll
    for (int s = 0; s < 4; ++s) qb[0][s] = *(const v4i*)(qbase + s * 16);
#pragma unroll
    for (int r = 0; r < 4; ++r) {
        const int row = r * 4 + wid;
        buf[0][row * 64 + (lane ^ (row & 7))] = wst[r];
    }
    asm volatile("s_waitcnt lgkmcnt(0)" ::: "memory");
    asm volatile("s_barrier" ::: "memory");

    // ---- main loop over 4 K-quarters ----
#pragma unroll
    for (int q = 0; q < 4; ++q) {
        if (q < 3) {
            // issue next-quarter weight loads (contiguous 1 KB/wave-round) + q loads
#pragma unroll
            for (int r = 0; r < 4; ++r) {
                const int row = r * 4 + wid;
                wst[r] = *(const v4i*)(wp + (size_t)(m0 + row) * KW + (q + 1) * QTR_W + lane * 4);
            }
#pragma unroll
            for (int s = 0; s < 4; ++s)
                qb[(q + 1) & 1][s] = *(const v4i*)(qbase + (q + 1) * QTR_W + s * 16);
        }
        // compute quarter q from buf[q&1] (HBM latency of next quarter hides under this)
#pragma unroll
        for (int s = 0; s < 4; ++s) {
            const int c = wid * 16 + s * 4 + lgrp;
            v4i wv = buf[q & 1][lrow * 64 + (c ^ (lrow & 7))];
            v4i bb;
            bb[0] = spread2(wv[0]); bb[1] = spread2(wv[1]);
            bb[2] = spread2(wv[2]); bb[3] = spread2(wv[3]);
            acc = __builtin_amdgcn_mfma_i32_16x16x64_i8(qb[q & 1][s], bb, acc, 0, 0, 0);
        }
        asm volatile("s_barrier" ::: "memory");  // all waves done reading buf[q&1]
        if (q < 3) {
#pragma unroll
            for (int r = 0; r < 4; ++r) {
                const int row = r * 4 + wid;
                buf[(q + 1) & 1][row * 64 + (lane ^ (row & 7))] = wst[r];
            }
            asm volatile("s_waitcnt lgkmcnt(0)" ::: "memory");
            asm volatile("s_barrier" ::: "memory");  // staging visible
        }
    }

    // ---- cross-wave reduce via LDS (reuse buf[0]) ----
    buf[0][wid * 64 + lane] = acc;
    asm volatile("s_waitcnt lgkmcnt(0)" ::: "memory");
    asm volatile("s_barrier" ::: "memory");

    // thread t -> output (b = t>>4, m = t&15); D layout: col=lane&15, row=(lane>>4)*4+reg
    const int b = t >> 4, m = t & 15;
    const int src_lane = ((b >> 2) << 4) | m;
    const int reg = b & 3;
    const int* red = (const int*)&buf[0][0];
    int sum = red[(0 * 64 + src_lane) * 4 + reg] + red[(1 * 64 + src_lane) * 4 + reg] +
              red[(2 * 64 + src_lane) * 4 + reg] + red[(3 * 64 + src_lane) * 4 + reg];
    const float val = (float)(sum - sumq[b]) * invs[b] * wscale[m0 / GROUP_ROWS];
    out[(size_t)b * M_DIM + m0 + m] = val;
}

extern "C" void kernel_launch(void* const* d_in, const int* in_sizes, int n_in,
                              void* d_out, int out_size, void* d_ws, size_t ws_size,
                              hipStream_t stream) {
    const float* inp    = (const float*)d_in[0];
    const int*   wp     = (const int*)d_in[1];
    const float* wscale = (const float*)d_in[2];
    float* out = (float*)d_out;

    int*   qg   = (int*)d_ws;               // 16384 words = 64 KB
    int*   sumq = qg + B_DIM * KW;          // 16 ints
    float* invs = (float*)(sumq + B_DIM);   // 16 floats

    quant_k<<<dim3(B_DIM), dim3(1024), 0, stream>>>(inp, qg, sumq, invs);
    gemm_k<<<dim3(M_DIM / 16), dim3(256), 0, stream>>>(wp, qg, sumq, invs, wscale, out);
}